// Round 18
// baseline (169.972 us; speedup 1.0000x reference)
//
#include <hip/hip_runtime.h>
#include <hip/hip_bf16.h>
#include <math.h>

#define B_   2
#define S_   2048
#define HID_ 1024
#define H_   16
#define D_   64
#define HD_  (H_ * D_)

typedef __attribute__((ext_vector_type(8))) short bf16x8;
typedef __attribute__((ext_vector_type(4))) short bf16x4;
typedef __attribute__((ext_vector_type(4))) float f32x4;
typedef __attribute__((ext_vector_type(4))) unsigned uint4v;
typedef unsigned short u16;

#define LOG2E 1.44269504088896f

static __device__ __forceinline__ u16 f2bf(float f) {
    unsigned u = __builtin_bit_cast(unsigned, f);
    u += 0x7fffu + ((u >> 16) & 1u);          // RNE
    return (u16)(u >> 16);
}
static __device__ __forceinline__ unsigned cvtpk(float lo, float hi) {
    unsigned r;
    asm("v_cvt_pk_bf16_f32 %0, %1, %2" : "=v"(r) : "v"(lo), "v"(hi));
    return r;
}
static __device__ __forceinline__ int swzV(int row, int colbytes) {
    return row * 128 + (colbytes ^ ((row & 7) << 4) ^ (((row >> 3) & 1) << 3));
}
static __device__ __forceinline__ void gll16(const void* g, void* l) {
    __builtin_amdgcn_global_load_lds(
        (const __attribute__((address_space(1))) unsigned int*)g,
        (__attribute__((address_space(3))) unsigned int*)l, 16, 0, 0);
}

// ---------------- fused preprocessing: x->bf16 AND 4x W transpose->bf16 ----------------
__global__ __launch_bounds__(256) void prep(const float* __restrict__ x,
                                            u16* __restrict__ xb,
                                            const float* __restrict__ W0,
                                            const float* __restrict__ W1,
                                            const float* __restrict__ W2,
                                            const float* __restrict__ W3,
                                            u16* __restrict__ o0,
                                            u16* __restrict__ o1,
                                            u16* __restrict__ o2,
                                            u16* __restrict__ o3) {
    __shared__ float tS[32][33];
    const int bid = blockIdx.x;
    if (bid < 4096) {                  // convert x: 1M float4s
        int i = bid * 256 + threadIdx.x;
        float4 f = ((const float4*)x)[i];
        ushort4 u;
        u.x = f2bf(f.x); u.y = f2bf(f.y); u.z = f2bf(f.z); u.w = f2bf(f.w);
        ((ushort4*)xb)[i] = u;
    } else {                           // transpose W: 4 x (32x32 grid of 32x32 tiles)
        const int id  = bid - 4096;
        const int z   = id >> 10;
        const int rem = id & 1023;
        const float* in = z == 0 ? W0 : z == 1 ? W1 : z == 2 ? W2 : W3;
        u16* out       = z == 0 ? o0 : z == 1 ? o1 : z == 2 ? o2 : o3;
        const int bx = (rem & 31) * 32, by = (rem >> 5) * 32;
        const int xx = threadIdx.x & 31, yy = threadIdx.x >> 5;
        #pragma unroll
        for (int j = 0; j < 4; j++)
            tS[yy + j * 8][xx] = in[(long)(by + yy + j * 8) * HID_ + bx + xx];
        __syncthreads();
        #pragma unroll
        for (int j = 0; j < 4; j++)
            out[(long)(bx + yy + j * 8) * HID_ + by + xx] = f2bf(tS[xx][yy + j * 8]);
    }
}

// ---------------- bf16 MFMA GEMM 128x128, BK=64, swizzled LDS (m173 pattern) ----------------
__global__ __launch_bounds__(256, 3) void gemm_qkv(const u16* __restrict__ A,
                                                   const u16* __restrict__ Bt,
                                                   u16* __restrict__ outb,
                                                   const float* __restrict__ cosb,
                                                   const float* __restrict__ sinb,
                                                   int K) {
    __shared__ u16 As[128 * 64];
    __shared__ u16 Bs[128 * 64];
    const int t = threadIdx.x;
    const int lane = t & 63;
    const int w = t >> 6;
    const int qlane = lane & 15, grp = lane >> 4;
    const int m0 = blockIdx.y * 128, n0 = blockIdx.x * 128;
    const int wr = w >> 1, wc = w & 1;

    f32x4 acc[4][4];
    #pragma unroll
    for (int i = 0; i < 4; i++)
        #pragma unroll
        for (int j = 0; j < 4; j++) acc[i][j] = (f32x4){0.f, 0.f, 0.f, 0.f};

    const int srow = lane >> 3;                  // 0..7 (row within 8-row chunk)
    const int scol = ((lane & 7) ^ srow) * 8;    // pre-swizzled source col (bf16)
    const int swa  = (qlane & 7) << 4;           // read-side XOR (bytes)
    const int nkt = K >> 6;
    for (int kt = 0; kt < nkt; kt++) {
        const int k0 = kt << 6;
        #pragma unroll
        for (int c = 0; c < 4; c++) {
            const int chunk = w * 4 + c;         // 16 chunks x 8 rows = 128 rows
            const int row = chunk * 8 + srow;
            gll16(A  + (long)(m0 + row) * K + k0 + scol, As + chunk * 512);
            gll16(Bt + (long)(n0 + row) * K + k0 + scol, Bs + chunk * 512);
        }
        __syncthreads();
        #pragma unroll
        for (int ks = 0; ks < 2; ks++) {
            bf16x8 af[4], bfr[4];
            #pragma unroll
            for (int i = 0; i < 4; i++) {
                af[i]  = *(const bf16x8*)((const unsigned char*)As
                         + (wr * 64 + i * 16 + qlane) * 128 + ((ks * 64 + grp * 16) ^ swa));
                bfr[i] = *(const bf16x8*)((const unsigned char*)Bs
                         + (wc * 64 + i * 16 + qlane) * 128 + ((ks * 64 + grp * 16) ^ swa));
            }
            #pragma unroll
            for (int mf = 0; mf < 4; mf++)
                #pragma unroll
                for (int nf = 0; nf < 4; nf++)
                    acc[mf][nf] = __builtin_amdgcn_mfma_f32_16x16x32_bf16(bfr[nf], af[mf], acc[mf][nf], 0, 0, 0);
        }
        __syncthreads();
    }

    const int gnb = n0 + wc * 64;
    const bool isqk = gnb < 2048;
    const bool isq  = gnb < 1024;
    const float QS = 0.125f * LOG2E;
    #pragma unroll
    for (int mf = 0; mf < 4; mf++) {
        const int m = m0 + wr * 64 + mf * 16 + qlane;
        if (isqk) {
            const int s = m & (S_ - 1);
            const float* cr = cosb + s * 64;
            const float* sr = sinb + s * 64;
            #pragma unroll
            for (int nf2 = 0; nf2 < 2; nf2++) {
                #pragma unroll
                for (int r = 0; r < 4; r++) {
                    const int d = nf2 * 16 + grp * 4 + r;
                    float lo = acc[mf][nf2][r], hi = acc[mf][nf2 + 2][r];
                    float nlo = lo * cr[d]      - hi * sr[d];
                    float nhi = hi * cr[d + 32] + lo * sr[d + 32];
                    if (isq) { nlo *= QS; nhi *= QS; }
                    acc[mf][nf2][r]     = nlo;
                    acc[mf][nf2 + 2][r] = nhi;
                }
            }
        }
        #pragma unroll
        for (int nf = 0; nf < 4; nf++) {
            const int gn = gnb + nf * 16 + grp * 4;
            ushort4 o4;
            o4.x = f2bf(acc[mf][nf][0]); o4.y = f2bf(acc[mf][nf][1]);
            o4.z = f2bf(acc[mf][nf][2]); o4.w = f2bf(acc[mf][nf][3]);
            *(ushort4*)&outb[((long)(gn >> 10)) * ((long)4096 * 1024) + (long)m * 1024 + (gn & 1023)] = o4;
        }
    }
}

// ---------------- bf16 MFMA GEMM 128x64, BK=64 swizzled (f32 out) for ctx @ Wo ----------------
__global__ __launch_bounds__(256, 3) void gemm_n64(const u16* __restrict__ A,
                                                   const u16* __restrict__ Bt,
                                                   float* __restrict__ outf,
                                                   int K) {
    __shared__ u16 As[128 * 64];
    __shared__ u16 Bs[64 * 64];
    const int t = threadIdx.x;
    const int lane = t & 63;
    const int w = t >> 6;
    const int qlane = lane & 15, grp = lane >> 4;
    const int m0 = blockIdx.y * 128, n0 = blockIdx.x * 64;

    f32x4 acc[2][4];
    #pragma unroll
    for (int i = 0; i < 2; i++)
        #pragma unroll
        for (int j = 0; j < 4; j++) acc[i][j] = (f32x4){0.f, 0.f, 0.f, 0.f};

    const int srow = lane >> 3;                  // 0..7
    const int scol = ((lane & 7) ^ srow) * 8;    // pre-swizzled source col
    const int swa  = (qlane & 7) << 4;
    const int nkt = K >> 6;
    for (int kt = 0; kt < nkt; kt++) {
        const int k0 = kt << 6;
        #pragma unroll
        for (int c = 0; c < 4; c++) {
            const int chunk = w * 4 + c;         // 16 chunks x 8 rows = 128 rows
            gll16(A + (long)(m0 + chunk * 8 + srow) * K + k0 + scol, As + chunk * 512);
        }
        #pragma unroll
        for (int c = 0; c < 2; c++) {
            const int chunk = w * 2 + c;         // 8 chunks x 8 rows = 64 rows
            gll16(Bt + (long)(n0 + chunk * 8 + srow) * K + k0 + scol, Bs + chunk * 512);
        }
        __syncthreads();
        #pragma unroll
        for (int ks = 0; ks < 2; ks++) {
            bf16x8 af[2], bfr[4];
            #pragma unroll
            for (int i = 0; i < 2; i++)
                af[i] = *(const bf16x8*)((const unsigned char*)As
                        + (w * 32 + i * 16 + qlane) * 128 + ((ks * 64 + grp * 16) ^ swa));
            #pragma unroll
            for (int i = 0; i < 4; i++)
                bfr[i] = *(const bf16x8*)((const unsigned char*)Bs
                         + (i * 16 + qlane) * 128 + ((ks * 64 + grp * 16) ^ swa));
            #pragma unroll
            for (int mf = 0; mf < 2; mf++)
                #pragma unroll
                for (int nf = 0; nf < 4; nf++)
                    acc[mf][nf] = __builtin_amdgcn_mfma_f32_16x16x32_bf16(bfr[nf], af[mf], acc[mf][nf], 0, 0, 0);
        }
        __syncthreads();
    }

    #pragma unroll
    for (int mf = 0; mf < 2; mf++) {
        const int m = m0 + w * 32 + mf * 16 + qlane;
        #pragma unroll
        for (int nf = 0; nf < 4; nf++) {
            float4 o4;
            o4.x = acc[mf][nf][0]; o4.y = acc[mf][nf][1];
            o4.z = acc[mf][nf][2]; o4.w = acc[mf][nf][3];
            *(float4*)&outf[(long)m * 1024 + n0 + nf * 16 + grp * 4] = o4;
        }
    }
}

// ---------------- MFMA flash attention: 8 waves x 16 q-rows, K direct from L2 ----------------
// K is L2-resident (256 KB/head, XCD-pinned via block swizzle): read QK fragments
// directly from global — removes the kS LDS round-trip (kreg load + ds_write +
// 8 ds_read per iter) whose only role was redistribution of L2-fit data
// (common-mistake #7). V (needs transpose) and bias stay LDS-staged; loop
// structure otherwise identical to the proven R14 body.
__global__ __launch_bounds__(512, 4) void attn_mfma(const u16* __restrict__ q,
                                                    const u16* __restrict__ k,
                                                    const u16* __restrict__ v,
                                                    const float* __restrict__ rel_bias,
                                                    u16* __restrict__ ctx) {
    __shared__ __align__(16) unsigned char vS[2][8192];   // V^T [d][k] bf16, swzV
    __shared__ float bb[2][192];

    const int t    = threadIdx.x;
    const int lane = t & 63;
    const int w    = t >> 6;                     // 0..7
    const int n    = blockIdx.x;                 // 512 blocks
    const int xcd  = n & 7;
    const int hbhi = (n >> 7) & 3;
    int qtb        = (n >> 3) & 15;
    if (hbhi & 2) qtb = 15 - qtb;                // zigzag load balance
    const int hb   = xcd + (hbhi << 3);          // 4 heads per XCD slot
    const int h    = hb & 15, b = hb >> 4;
    const int q0   = qtb * 128;
    const int wq   = w * 16;
    const int qwq  = q0 + wq;
    const int qlane = lane & 15;
    const int grp   = lane >> 4;

    const long bhbase = ((long)b * S_ * H_ + h) * D_;
    const float bfar  = rel_bias[31 * H_ + h] * LOG2E;

    // V staging coords
    const int vrb = (t >> 5) * 4,  vcp = (t & 31) * 2;   // V: 4 rows x 2 cols

    bf16x8 qf0, qf1;
    {
        const u16* qrow = q + bhbase + (long)(qwq + qlane) * HD_;
        qf0 = *(const bf16x8*)(qrow + grp * 8);
        qf1 = *(const bf16x8*)(qrow + 32 + grp * 8);
    }
    // per-lane K fragment base: row offset qlane, col grp*8 (and +32 for kf1)
    const u16* kfb = k + bhbase + (long)qlane * HD_ + grp * 8;

    f32x4 oacc[4];                                // O^T: row d, col q=qlane
    #pragma unroll
    for (int db = 0; db < 4; db++) oacc[db] = (f32x4){0.f, 0.f, 0.f, 0.f};
    float m_run = -1.0e30f, l_run = 0.f;

    unsigned vreg[4];
    float breg = 0.f;

    auto prefetch = [&](int k0, bool needb) {
        const u16* vp = v + bhbase + (long)(k0 + vrb) * HD_ + vcp;
        #pragma unroll
        for (int i = 0; i < 4; i++)
            vreg[i] = *(const unsigned*)(vp + (long)i * HD_);
        if (needb && t < 192) {
            int rp = (q0 - 63) + t - k0;
            float bv = 0.f;
            if (rp >= 0) {
                int bucket;
                if (rp < 16) bucket = rp;
                else {
                    int lg = (int)(logf((float)rp * 0.0625f) * 7.69437361f);
                    bucket = 16 + lg;
                    if (bucket > 31) bucket = 31;
                }
                bv = rel_bias[bucket * H_ + h] * LOG2E;
            }
            breg = bv;
        }
    };
    auto writetile = [&](int buf, bool needb) {
        ushort2 a0 = __builtin_bit_cast(ushort2, vreg[0]);
        ushort2 a1 = __builtin_bit_cast(ushort2, vreg[1]);
        ushort2 a2 = __builtin_bit_cast(ushort2, vreg[2]);
        ushort2 a3 = __builtin_bit_cast(ushort2, vreg[3]);
        ushort4 d0; d0.x = a0.x; d0.y = a1.x; d0.z = a2.x; d0.w = a3.x;
        ushort4 d1; d1.x = a0.y; d1.y = a1.y; d1.z = a2.y; d1.w = a3.y;
        *(ushort4*)(vS[buf] + swzV(vcp,     vrb * 2)) = d0;
        *(ushort4*)(vS[buf] + swzV(vcp + 1, vrb * 2)) = d1;
        if (needb && t < 192) bb[buf][t] = breg;
    };

    const int NT = 2 * qtb + 2;
    const bool needb0 = (q0 < 176);
    prefetch(0, needb0);
    writetile(0, needb0);
    __syncthreads();

    int cur = 0;
    for (int kt = 0; kt < NT; kt++) {
        const int k0 = kt * 64;
        const bool has_next = (kt + 1) < NT;
        const bool needb_n  = (q0 - (k0 + 64)) < 176;
        if (has_next) prefetch(k0 + 64, needb_n);

        const bool skip = k0 > qwq + 15;
        if (!skip) {
            const bool use_bias = (qwq - k0) < 176;
            const bool is_diag  = (k0 + 63) > qwq;

            // ---- QK: K fragments direct from global (L2-hit; shared across waves) ----
            __builtin_amdgcn_s_setprio(1);
            f32x4 sacc[4];
            #pragma unroll
            for (int kb = 0; kb < 4; kb++) {
                sacc[kb] = (f32x4){0.f, 0.f, 0.f, 0.f};
                const u16* kp = kfb + (long)(k0 + kb * 16) * HD_;
                bf16x8 kf0 = *(const bf16x8*)kp;
                bf16x8 kf1 = *(const bf16x8*)(kp + 32);
                sacc[kb] = __builtin_amdgcn_mfma_f32_16x16x32_bf16(kf0, qf0, sacc[kb], 0, 0, 0);
                sacc[kb] = __builtin_amdgcn_mfma_f32_16x16x32_bf16(kf1, qf1, sacc[kb], 0, 0, 0);
            }
            __builtin_amdgcn_s_setprio(0);

            float pv_[4][4];
            float tmax = -1.0e30f;
            #pragma unroll
            for (int kb = 0; kb < 4; kb++) {
                #pragma unroll
                for (int r = 0; r < 4; r++) {
                    float s = sacc[kb][r];               // log2 domain
                    if (use_bias) {
                        const int k_l = kb * 16 + grp * 4 + r;
                        s += bb[cur][wq + qlane - k_l + 63];
                        if (is_diag)
                            s = ((k0 + k_l) <= (qwq + qlane)) ? s : -1.0e9f;
                    }
                    pv_[kb][r] = s;
                }
                tmax = fmaxf(tmax,
                       fmaxf(fmaxf(pv_[kb][0], pv_[kb][1]), fmaxf(pv_[kb][2], pv_[kb][3])));
            }
            tmax = fmaxf(tmax, __shfl_xor(tmax, 16));
            tmax = fmaxf(tmax, __shfl_xor(tmax, 32));

            const float bofs = use_bias ? 0.f : bfar;
            const float teff = tmax + bofs;
            float msub;
            if (__all(teff <= m_run + 11.5f)) {          // defer (2^11.5 ~ e^8)
                msub = m_run - bofs;
            } else {
                float mnew  = fmaxf(m_run, teff);
                float scale = __builtin_amdgcn_exp2f(m_run - mnew);
                l_run *= scale;
                #pragma unroll
                for (int db = 0; db < 4; db++)
                    #pragma unroll
                    for (int r = 0; r < 4; r++) oacc[db][r] *= scale;   // per-lane q
                m_run = mnew;
                msub = mnew - bofs;
            }

            float tsum = 0.f;
            #pragma unroll
            for (int kb = 0; kb < 4; kb++)
                #pragma unroll
                for (int r = 0; r < 4; r++) {
                    float p = __builtin_amdgcn_exp2f(pv_[kb][r] - msub);
                    pv_[kb][r] = p;
                    tsum += p;
                }
            tsum += __shfl_xor(tsum, 16);
            tsum += __shfl_xor(tsum, 32);
            l_run += tsum;

            bf16x8 pf[2];
            #pragma unroll
            for (int ks = 0; ks < 2; ks++) {
                unsigned u0 = cvtpk(pv_[2 * ks][0], pv_[2 * ks][1]);
                unsigned u1 = cvtpk(pv_[2 * ks][2], pv_[2 * ks][3]);
                unsigned u2 = cvtpk(pv_[2 * ks + 1][0], pv_[2 * ks + 1][1]);
                unsigned u3 = cvtpk(pv_[2 * ks + 1][2], pv_[2 * ks + 1][3]);
                pf[ks] = __builtin_bit_cast(bf16x8, (uint4v){u0, u1, u2, u3});
            }

            __builtin_amdgcn_s_setprio(1);
            #pragma unroll
            for (int db = 0; db < 4; db++) {
                #pragma unroll
                for (int ks = 0; ks < 2; ks++) {
                    bf16x4 lo = *(const bf16x4*)(vS[cur] + swzV(db * 16 + qlane, ks * 64 + grp * 8));
                    bf16x4 hi = *(const bf16x4*)(vS[cur] + swzV(db * 16 + qlane, ks * 64 + 32 + grp * 8));
                    bf16x8 vf = __builtin_shufflevector(lo, hi, 0, 1, 2, 3, 4, 5, 6, 7);
                    oacc[db] = __builtin_amdgcn_mfma_f32_16x16x32_bf16(vf, pf[ks], oacc[db], 0, 0, 0);
                }
            }
            __builtin_amdgcn_s_setprio(0);
        }

        if (has_next) writetile(cur ^ 1, needb_n);
        __syncthreads();
        cur ^= 1;
    }

    // ---- epilogue: per-lane 1/l; O^T row d = db*16+grp*4+r, col q = qlane ----
    const float inv = 1.0f / l_run;
    u16* dst = ctx + (long)(b * S_ + qwq + qlane) * HID_ + h * D_;
    #pragma unroll
    for (int db = 0; db < 4; db++) {
        ushort4 o4;
        o4.x = f2bf(oacc[db][0] * inv);
        o4.y = f2bf(oacc[db][1] * inv);
        o4.z = f2bf(oacc[db][2] * inv);
        o4.w = f2bf(oacc[db][3] * inv);
        *(ushort4*)(dst + db * 16 + grp * 4) = o4;
    }
}

extern "C" void kernel_launch(void* const* d_in, const int* in_sizes, int n_in,
                              void* d_out, int out_size, void* d_ws, size_t ws_size,
                              hipStream_t stream) {
    const float* x    = (const float*)d_in[0];
    const float* Wq   = (const float*)d_in[1];
    const float* Wk   = (const float*)d_in[2];
    const float* Wv   = (const float*)d_in[3];
    const float* Wo   = (const float*)d_in[4];
    const float* rb   = (const float*)d_in[5];
    const float* cosb = (const float*)d_in[6];
    const float* sinb = (const float*)d_in[7];
    float* out = (float*)d_out;

    char* wsb = (char*)d_ws;
    u16* xb    = (u16*)(wsb);
    u16* wqkvT = (u16*)(wsb + (8L  << 20));
    u16* woT   = (u16*)(wsb + (14L << 20));
    u16* qb    = (u16*)(wsb + (16L << 20));
    u16* kb    = (u16*)(wsb + (24L << 20));
    u16* vb    = (u16*)(wsb + (32L << 20));
    u16* ctxb  = (u16*)(wsb + (40L << 20));

    hipLaunchKernelGGL(prep, dim3(4096 + 4096), dim3(256), 0, stream,
                       x, xb, Wq, Wk, Wv, Wo,
                       wqkvT, wqkvT + (1L << 20), wqkvT + (2L << 20), woT);
    hipLaunchKernelGGL(gemm_qkv, dim3(24, 32), dim3(256), 0, stream,
                       xb, wqkvT, qb, cosb, sinb, HID_);
    hipLaunchKernelGGL(attn_mfma, dim3(512), dim3(512), 0, stream,
                       qb, kb, vb, rb, ctxb);
    hipLaunchKernelGGL(gemm_n64, dim3(16, 32), dim3(256), 0, stream,
                       ctxb, woT, out, HID_);
}

// Round 19
// 117.709 us; speedup vs baseline: 1.4440x; 1.4440x over previous
//
#include <hip/hip_runtime.h>
#include <hip/hip_bf16.h>
#include <math.h>

#define B_   2
#define S_   2048
#define HID_ 1024
#define H_   16
#define D_   64
#define HD_  (H_ * D_)

typedef __attribute__((ext_vector_type(8))) short bf16x8;
typedef __attribute__((ext_vector_type(4))) short bf16x4;
typedef __attribute__((ext_vector_type(4))) float f32x4;
typedef __attribute__((ext_vector_type(4))) unsigned uint4v;
typedef unsigned short u16;

#define LOG2E 1.44269504088896f

static __device__ __forceinline__ u16 f2bf(float f) {
    unsigned u = __builtin_bit_cast(unsigned, f);
    u += 0x7fffu + ((u >> 16) & 1u);          // RNE
    return (u16)(u >> 16);
}
static __device__ __forceinline__ unsigned cvtpk(float lo, float hi) {
    unsigned r;
    asm("v_cvt_pk_bf16_f32 %0, %1, %2" : "=v"(r) : "v"(lo), "v"(hi));
    return r;
}
static __device__ __forceinline__ int swzK(int row, int colbytes) {
    return row * 128 + (colbytes ^ ((row & 7) << 4));
}
static __device__ __forceinline__ int swzV(int row, int colbytes) {
    return row * 128 + (colbytes ^ ((row & 7) << 4) ^ (((row >> 3) & 1) << 3));
}
static __device__ __forceinline__ void gll16(const void* g, void* l) {
    __builtin_amdgcn_global_load_lds(
        (const __attribute__((address_space(1))) unsigned int*)g,
        (__attribute__((address_space(3))) unsigned int*)l, 16, 0, 0);
}

// ---------------- fused preprocessing: x->bf16 AND 4x W transpose->bf16 ----------------
__global__ __launch_bounds__(256) void prep(const float* __restrict__ x,
                                            u16* __restrict__ xb,
                                            const float* __restrict__ W0,
                                            const float* __restrict__ W1,
                                            const float* __restrict__ W2,
                                            const float* __restrict__ W3,
                                            u16* __restrict__ o0,
                                            u16* __restrict__ o1,
                                            u16* __restrict__ o2,
                                            u16* __restrict__ o3) {
    __shared__ float tS[32][33];
    const int bid = blockIdx.x;
    if (bid < 4096) {                  // convert x: 1M float4s
        int i = bid * 256 + threadIdx.x;
        float4 f = ((const float4*)x)[i];
        ushort4 u;
        u.x = f2bf(f.x); u.y = f2bf(f.y); u.z = f2bf(f.z); u.w = f2bf(f.w);
        ((ushort4*)xb)[i] = u;
    } else {                           // transpose W: 4 x (32x32 grid of 32x32 tiles)
        const int id  = bid - 4096;
        const int z   = id >> 10;
        const int rem = id & 1023;
        const float* in = z == 0 ? W0 : z == 1 ? W1 : z == 2 ? W2 : W3;
        u16* out       = z == 0 ? o0 : z == 1 ? o1 : z == 2 ? o2 : o3;
        const int bx = (rem & 31) * 32, by = (rem >> 5) * 32;
        const int xx = threadIdx.x & 31, yy = threadIdx.x >> 5;
        #pragma unroll
        for (int j = 0; j < 4; j++)
            tS[yy + j * 8][xx] = in[(long)(by + yy + j * 8) * HID_ + bx + xx];
        __syncthreads();
        #pragma unroll
        for (int j = 0; j < 4; j++)
            out[(long)(bx + yy + j * 8) * HID_ + by + xx] = f2bf(tS[xx][yy + j * 8]);
    }
}

// ---------------- bf16 MFMA GEMM 128x128, BK=64, swizzled LDS (m173 pattern) ----------------
__global__ __launch_bounds__(256, 3) void gemm_qkv(const u16* __restrict__ A,
                                                   const u16* __restrict__ Bt,
                                                   u16* __restrict__ outb,
                                                   const float* __restrict__ cosb,
                                                   const float* __restrict__ sinb,
                                                   int K) {
    __shared__ u16 As[128 * 64];
    __shared__ u16 Bs[128 * 64];
    const int t = threadIdx.x;
    const int lane = t & 63;
    const int w = t >> 6;
    const int qlane = lane & 15, grp = lane >> 4;
    const int m0 = blockIdx.y * 128, n0 = blockIdx.x * 128;
    const int wr = w >> 1, wc = w & 1;

    f32x4 acc[4][4];
    #pragma unroll
    for (int i = 0; i < 4; i++)
        #pragma unroll
        for (int j = 0; j < 4; j++) acc[i][j] = (f32x4){0.f, 0.f, 0.f, 0.f};

    const int srow = lane >> 3;                  // 0..7 (row within 8-row chunk)
    const int scol = ((lane & 7) ^ srow) * 8;    // pre-swizzled source col (bf16)
    const int swa  = (qlane & 7) << 4;           // read-side XOR (bytes)
    const int nkt = K >> 6;
    for (int kt = 0; kt < nkt; kt++) {
        const int k0 = kt << 6;
        #pragma unroll
        for (int c = 0; c < 4; c++) {
            const int chunk = w * 4 + c;         // 16 chunks x 8 rows = 128 rows
            const int row = chunk * 8 + srow;
            gll16(A  + (long)(m0 + row) * K + k0 + scol, As + chunk * 512);
            gll16(Bt + (long)(n0 + row) * K + k0 + scol, Bs + chunk * 512);
        }
        __syncthreads();
        #pragma unroll
        for (int ks = 0; ks < 2; ks++) {
            bf16x8 af[4], bfr[4];
            #pragma unroll
            for (int i = 0; i < 4; i++) {
                af[i]  = *(const bf16x8*)((const unsigned char*)As
                         + (wr * 64 + i * 16 + qlane) * 128 + ((ks * 64 + grp * 16) ^ swa));
                bfr[i] = *(const bf16x8*)((const unsigned char*)Bs
                         + (wc * 64 + i * 16 + qlane) * 128 + ((ks * 64 + grp * 16) ^ swa));
            }
            #pragma unroll
            for (int mf = 0; mf < 4; mf++)
                #pragma unroll
                for (int nf = 0; nf < 4; nf++)
                    acc[mf][nf] = __builtin_amdgcn_mfma_f32_16x16x32_bf16(bfr[nf], af[mf], acc[mf][nf], 0, 0, 0);
        }
        __syncthreads();
    }

    const int gnb = n0 + wc * 64;
    const bool isqk = gnb < 2048;
    const bool isq  = gnb < 1024;
    const float QS = 0.125f * LOG2E;
    #pragma unroll
    for (int mf = 0; mf < 4; mf++) {
        const int m = m0 + wr * 64 + mf * 16 + qlane;
        if (isqk) {
            const int s = m & (S_ - 1);
            const float* cr = cosb + s * 64;
            const float* sr = sinb + s * 64;
            #pragma unroll
            for (int nf2 = 0; nf2 < 2; nf2++) {
                #pragma unroll
                for (int r = 0; r < 4; r++) {
                    const int d = nf2 * 16 + grp * 4 + r;
                    float lo = acc[mf][nf2][r], hi = acc[mf][nf2 + 2][r];
                    float nlo = lo * cr[d]      - hi * sr[d];
                    float nhi = hi * cr[d + 32] + lo * sr[d + 32];
                    if (isq) { nlo *= QS; nhi *= QS; }
                    acc[mf][nf2][r]     = nlo;
                    acc[mf][nf2 + 2][r] = nhi;
                }
            }
        }
        #pragma unroll
        for (int nf = 0; nf < 4; nf++) {
            const int gn = gnb + nf * 16 + grp * 4;
            ushort4 o4;
            o4.x = f2bf(acc[mf][nf][0]); o4.y = f2bf(acc[mf][nf][1]);
            o4.z = f2bf(acc[mf][nf][2]); o4.w = f2bf(acc[mf][nf][3]);
            *(ushort4*)&outb[((long)(gn >> 10)) * ((long)4096 * 1024) + (long)m * 1024 + (gn & 1023)] = o4;
        }
    }
}

// ---------------- bf16 MFMA GEMM 128x64, BK=64 swizzled (f32 out) for ctx @ Wo ----------------
__global__ __launch_bounds__(256, 3) void gemm_n64(const u16* __restrict__ A,
                                                   const u16* __restrict__ Bt,
                                                   float* __restrict__ outf,
                                                   int K) {
    __shared__ u16 As[128 * 64];
    __shared__ u16 Bs[64 * 64];
    const int t = threadIdx.x;
    const int lane = t & 63;
    const int w = t >> 6;
    const int qlane = lane & 15, grp = lane >> 4;
    const int m0 = blockIdx.y * 128, n0 = blockIdx.x * 64;

    f32x4 acc[2][4];
    #pragma unroll
    for (int i = 0; i < 2; i++)
        #pragma unroll
        for (int j = 0; j < 4; j++) acc[i][j] = (f32x4){0.f, 0.f, 0.f, 0.f};

    const int srow = lane >> 3;                  // 0..7
    const int scol = ((lane & 7) ^ srow) * 8;    // pre-swizzled source col
    const int swa  = (qlane & 7) << 4;
    const int nkt = K >> 6;
    for (int kt = 0; kt < nkt; kt++) {
        const int k0 = kt << 6;
        #pragma unroll
        for (int c = 0; c < 4; c++) {
            const int chunk = w * 4 + c;         // 16 chunks x 8 rows = 128 rows
            gll16(A + (long)(m0 + chunk * 8 + srow) * K + k0 + scol, As + chunk * 512);
        }
        #pragma unroll
        for (int c = 0; c < 2; c++) {
            const int chunk = w * 2 + c;         // 8 chunks x 8 rows = 64 rows
            gll16(Bt + (long)(n0 + chunk * 8 + srow) * K + k0 + scol, Bs + chunk * 512);
        }
        __syncthreads();
        #pragma unroll
        for (int ks = 0; ks < 2; ks++) {
            bf16x8 af[2], bfr[4];
            #pragma unroll
            for (int i = 0; i < 2; i++)
                af[i] = *(const bf16x8*)((const unsigned char*)As
                        + (w * 32 + i * 16 + qlane) * 128 + ((ks * 64 + grp * 16) ^ swa));
            #pragma unroll
            for (int i = 0; i < 4; i++)
                bfr[i] = *(const bf16x8*)((const unsigned char*)Bs
                         + (i * 16 + qlane) * 128 + ((ks * 64 + grp * 16) ^ swa));
            #pragma unroll
            for (int mf = 0; mf < 2; mf++)
                #pragma unroll
                for (int nf = 0; nf < 4; nf++)
                    acc[mf][nf] = __builtin_amdgcn_mfma_f32_16x16x32_bf16(bfr[nf], af[mf], acc[mf][nf], 0, 0, 0);
        }
        __syncthreads();
    }

    #pragma unroll
    for (int mf = 0; mf < 2; mf++) {
        const int m = m0 + w * 32 + mf * 16 + qlane;
        #pragma unroll
        for (int nf = 0; nf < 4; nf++) {
            float4 o4;
            o4.x = acc[mf][nf][0]; o4.y = acc[mf][nf][1];
            o4.z = acc[mf][nf][2]; o4.w = acc[mf][nf][3];
            *(float4*)&outf[(long)m * 1024 + n0 + nf * 16 + grp * 4] = o4;
        }
    }
}

// ---------------- MFMA flash attention: 8 waves x 16 q-rows (R8/R12/R14 body, proven) ----------------
__global__ __launch_bounds__(512, 4) void attn_mfma(const u16* __restrict__ q,
                                                    const u16* __restrict__ k,
                                                    const u16* __restrict__ v,
                                                    const float* __restrict__ rel_bias,
                                                    u16* __restrict__ ctx) {
    __shared__ __align__(16) unsigned char kS[2][8192];   // K [k][d] bf16, swzK
    __shared__ __align__(16) unsigned char vS[2][8192];   // V^T [d][k] bf16, swzV
    __shared__ float bb[2][192];

    const int t    = threadIdx.x;
    const int lane = t & 63;
    const int w    = t >> 6;                     // 0..7
    const int n    = blockIdx.x;                 // 512 blocks
    const int xcd  = n & 7;
    const int hbhi = (n >> 7) & 3;
    int qtb        = (n >> 3) & 15;
    if (hbhi & 2) qtb = 15 - qtb;                // zigzag load balance
    const int hb   = xcd + (hbhi << 3);          // 4 heads per XCD slot
    const int h    = hb & 15, b = hb >> 4;
    const int q0   = qtb * 128;
    const int wq   = w * 16;
    const int qwq  = q0 + wq;
    const int qlane = lane & 15;
    const int grp   = lane >> 4;

    const long bhbase = ((long)b * S_ * H_ + h) * D_;
    const float bfar  = rel_bias[31 * H_ + h] * LOG2E;

    // staging coords
    const int kr  = t >> 3,        kc  = (t & 7) * 8;    // K: 1 row, 8 cols (b128)
    const int vrb = (t >> 5) * 4,  vcp = (t & 31) * 2;   // V: 4 rows x 2 cols

    bf16x8 qf0, qf1;
    {
        const u16* qrow = q + bhbase + (long)(qwq + qlane) * HD_;
        qf0 = *(const bf16x8*)(qrow + grp * 8);
        qf1 = *(const bf16x8*)(qrow + 32 + grp * 8);
    }

    f32x4 oacc[4];                                // O^T: row d, col q=qlane
    #pragma unroll
    for (int db = 0; db < 4; db++) oacc[db] = (f32x4){0.f, 0.f, 0.f, 0.f};
    float m_run = -1.0e30f, l_run = 0.f;

    bf16x8 kreg;
    unsigned vreg[4];
    float breg = 0.f;

    auto prefetch = [&](int k0, bool needb) {
        kreg = *(const bf16x8*)(k + bhbase + (long)(k0 + kr) * HD_ + kc);
        const u16* vp = v + bhbase + (long)(k0 + vrb) * HD_ + vcp;
        #pragma unroll
        for (int i = 0; i < 4; i++)
            vreg[i] = *(const unsigned*)(vp + (long)i * HD_);
        if (needb && t < 192) {
            int rp = (q0 - 63) + t - k0;
            float bv = 0.f;
            if (rp >= 0) {
                int bucket;
                if (rp < 16) bucket = rp;
                else {
                    int lg = (int)(logf((float)rp * 0.0625f) * 7.69437361f);
                    bucket = 16 + lg;
                    if (bucket > 31) bucket = 31;
                }
                bv = rel_bias[bucket * H_ + h] * LOG2E;
            }
            breg = bv;
        }
    };
    auto writetile = [&](int buf, bool needb) {
        *(bf16x8*)(kS[buf] + swzK(kr, kc * 2)) = kreg;
        ushort2 a0 = __builtin_bit_cast(ushort2, vreg[0]);
        ushort2 a1 = __builtin_bit_cast(ushort2, vreg[1]);
        ushort2 a2 = __builtin_bit_cast(ushort2, vreg[2]);
        ushort2 a3 = __builtin_bit_cast(ushort2, vreg[3]);
        ushort4 d0; d0.x = a0.x; d0.y = a1.x; d0.z = a2.x; d0.w = a3.x;
        ushort4 d1; d1.x = a0.y; d1.y = a1.y; d1.z = a2.y; d1.w = a3.y;
        *(ushort4*)(vS[buf] + swzV(vcp,     vrb * 2)) = d0;
        *(ushort4*)(vS[buf] + swzV(vcp + 1, vrb * 2)) = d1;
        if (needb && t < 192) bb[buf][t] = breg;
    };

    const int NT = 2 * qtb + 2;
    const bool needb0 = (q0 < 176);
    prefetch(0, needb0);
    writetile(0, needb0);
    __syncthreads();

    int cur = 0;
    for (int kt = 0; kt < NT; kt++) {
        const int k0 = kt * 64;
        const bool has_next = (kt + 1) < NT;
        const bool needb_n  = (q0 - (k0 + 64)) < 176;
        if (has_next) prefetch(k0 + 64, needb_n);

        const bool skip = k0 > qwq + 15;
        if (!skip) {
            const bool use_bias = (qwq - k0) < 176;
            const bool is_diag  = (k0 + 63) > qwq;

            __builtin_amdgcn_s_setprio(1);
            f32x4 sacc[4];
            #pragma unroll
            for (int kb = 0; kb < 4; kb++) {
                sacc[kb] = (f32x4){0.f, 0.f, 0.f, 0.f};
                bf16x8 kf0 = *(const bf16x8*)(kS[cur] + swzK(kb * 16 + qlane, grp * 16));
                bf16x8 kf1 = *(const bf16x8*)(kS[cur] + swzK(kb * 16 + qlane, 64 + grp * 16));
                sacc[kb] = __builtin_amdgcn_mfma_f32_16x16x32_bf16(kf0, qf0, sacc[kb], 0, 0, 0);
                sacc[kb] = __builtin_amdgcn_mfma_f32_16x16x32_bf16(kf1, qf1, sacc[kb], 0, 0, 0);
            }
            __builtin_amdgcn_s_setprio(0);

            float pv_[4][4];
            float tmax = -1.0e30f;
            #pragma unroll
            for (int kb = 0; kb < 4; kb++) {
                #pragma unroll
                for (int r = 0; r < 4; r++) {
                    float s = sacc[kb][r];               // log2 domain
                    if (use_bias) {
                        const int k_l = kb * 16 + grp * 4 + r;
                        s += bb[cur][wq + qlane - k_l + 63];
                        if (is_diag)
                            s = ((k0 + k_l) <= (qwq + qlane)) ? s : -1.0e9f;
                    }
                    pv_[kb][r] = s;
                }
                tmax = fmaxf(tmax,
                       fmaxf(fmaxf(pv_[kb][0], pv_[kb][1]), fmaxf(pv_[kb][2], pv_[kb][3])));
            }
            tmax = fmaxf(tmax, __shfl_xor(tmax, 16));
            tmax = fmaxf(tmax, __shfl_xor(tmax, 32));

            const float bofs = use_bias ? 0.f : bfar;
            const float teff = tmax + bofs;
            float msub;
            if (__all(teff <= m_run + 11.5f)) {          // defer (2^11.5 ~ e^8)
                msub = m_run - bofs;
            } else {
                float mnew  = fmaxf(m_run, teff);
                float scale = __builtin_amdgcn_exp2f(m_run - mnew);
                l_run *= scale;
                #pragma unroll
                for (int db = 0; db < 4; db++)
                    #pragma unroll
                    for (int r = 0; r < 4; r++) oacc[db][r] *= scale;   // per-lane q
                m_run = mnew;
                msub = mnew - bofs;
            }

            float tsum = 0.f;
            #pragma unroll
            for (int kb = 0; kb < 4; kb++)
                #pragma unroll
                for (int r = 0; r < 4; r++) {
                    float p = __builtin_amdgcn_exp2f(pv_[kb][r] - msub);
                    pv_[kb][r] = p;
                    tsum += p;
                }
            tsum += __shfl_xor(tsum, 16);
            tsum += __shfl_xor(tsum, 32);
            l_run += tsum;

            bf16x8 pf[2];
            #pragma unroll
            for (int ks = 0; ks < 2; ks++) {
                unsigned u0 = cvtpk(pv_[2 * ks][0], pv_[2 * ks][1]);
                unsigned u1 = cvtpk(pv_[2 * ks][2], pv_[2 * ks][3]);
                unsigned u2 = cvtpk(pv_[2 * ks + 1][0], pv_[2 * ks + 1][1]);
                unsigned u3 = cvtpk(pv_[2 * ks + 1][2], pv_[2 * ks + 1][3]);
                pf[ks] = __builtin_bit_cast(bf16x8, (uint4v){u0, u1, u2, u3});
            }

            __builtin_amdgcn_s_setprio(1);
            #pragma unroll
            for (int db = 0; db < 4; db++) {
                #pragma unroll
                for (int ks = 0; ks < 2; ks++) {
                    bf16x4 lo = *(const bf16x4*)(vS[cur] + swzV(db * 16 + qlane, ks * 64 + grp * 8));
                    bf16x4 hi = *(const bf16x4*)(vS[cur] + swzV(db * 16 + qlane, ks * 64 + 32 + grp * 8));
                    bf16x8 vf = __builtin_shufflevector(lo, hi, 0, 1, 2, 3, 4, 5, 6, 7);
                    oacc[db] = __builtin_amdgcn_mfma_f32_16x16x32_bf16(vf, pf[ks], oacc[db], 0, 0, 0);
                }
            }
            __builtin_amdgcn_s_setprio(0);
        }

        if (has_next) writetile(cur ^ 1, needb_n);
        __syncthreads();
        cur ^= 1;
    }

    // ---- epilogue: per-lane 1/l; O^T row d = db*16+grp*4+r, col q = qlane ----
    const float inv = 1.0f / l_run;
    u16* dst = ctx + (long)(b * S_ + qwq + qlane) * HID_ + h * D_;
    #pragma unroll
    for (int db = 0; db < 4; db++) {
        ushort4 o4;
        o4.x = f2bf(oacc[db][0] * inv);
        o4.y = f2bf(oacc[db][1] * inv);
        o4.z = f2bf(oacc[db][2] * inv);
        o4.w = f2bf(oacc[db][3] * inv);
        *(ushort4*)(dst + db * 16 + grp * 4) = o4;
    }
}

extern "C" void kernel_launch(void* const* d_in, const int* in_sizes, int n_in,
                              void* d_out, int out_size, void* d_ws, size_t ws_size,
                              hipStream_t stream) {
    const float* x    = (const float*)d_in[0];
    const float* Wq   = (const float*)d_in[1];
    const float* Wk   = (const float*)d_in[2];
    const float* Wv   = (const float*)d_in[3];
    const float* Wo   = (const float*)d_in[4];
    const float* rb   = (const float*)d_in[5];
    const float* cosb = (const float*)d_in[6];
    const float* sinb = (const float*)d_in[7];
    float* out = (float*)d_out;

    char* wsb = (char*)d_ws;
    u16* xb    = (u16*)(wsb);
    u16* wqkvT = (u16*)(wsb + (8L  << 20));
    u16* woT   = (u16*)(wsb + (14L << 20));
    u16* qb    = (u16*)(wsb + (16L << 20));
    u16* kb    = (u16*)(wsb + (24L << 20));
    u16* vb    = (u16*)(wsb + (32L << 20));
    u16* ctxb  = (u16*)(wsb + (40L << 20));

    hipLaunchKernelGGL(prep, dim3(4096 + 4096), dim3(256), 0, stream,
                       x, xb, Wq, Wk, Wv, Wo,
                       wqkvT, wqkvT + (1L << 20), wqkvT + (2L << 20), woT);
    hipLaunchKernelGGL(gemm_qkv, dim3(24, 32), dim3(256), 0, stream,
                       xb, wqkvT, qb, cosb, sinb, HID_);
    hipLaunchKernelGGL(attn_mfma, dim3(512), dim3(512), 0, stream,
                       qb, kb, vb, rb, ctxb);
    hipLaunchKernelGGL(gemm_n64, dim3(16, 32), dim3(256), 0, stream,
                       ctxb, woT, out, HID_);
}

// Round 20
// 116.684 us; speedup vs baseline: 1.4567x; 1.0088x over previous
//
#include <hip/hip_runtime.h>
#include <hip/hip_bf16.h>
#include <math.h>

#define B_   2
#define S_   2048
#define HID_ 1024
#define H_   16
#define D_   64
#define HD_  (H_ * D_)

typedef __attribute__((ext_vector_type(8))) short bf16x8;
typedef __attribute__((ext_vector_type(4))) short bf16x4;
typedef __attribute__((ext_vector_type(4))) float f32x4;
typedef __attribute__((ext_vector_type(4))) unsigned uint4v;
typedef unsigned short u16;

#define LOG2E 1.44269504088896f

static __device__ __forceinline__ u16 f2bf(float f) {
    unsigned u = __builtin_bit_cast(unsigned, f);
    u += 0x7fffu + ((u >> 16) & 1u);          // RNE
    return (u16)(u >> 16);
}
static __device__ __forceinline__ unsigned cvtpk(float lo, float hi) {
    unsigned r;
    asm("v_cvt_pk_bf16_f32 %0, %1, %2" : "=v"(r) : "v"(lo), "v"(hi));
    return r;
}
static __device__ __forceinline__ int swzK(int row, int colbytes) {
    return row * 128 + (colbytes ^ ((row & 7) << 4));
}
static __device__ __forceinline__ int swzV(int row, int colbytes) {
    return row * 128 + (colbytes ^ ((row & 7) << 4) ^ (((row >> 3) & 1) << 3));
}
static __device__ __forceinline__ void gll16(const void* g, void* l) {
    __builtin_amdgcn_global_load_lds(
        (const __attribute__((address_space(1))) unsigned int*)g,
        (__attribute__((address_space(3))) unsigned int*)l, 16, 0, 0);
}

// ---------------- fused preprocessing: x->bf16 AND 4x W transpose->bf16 ----------------
__global__ __launch_bounds__(256) void prep(const float* __restrict__ x,
                                            u16* __restrict__ xb,
                                            const float* __restrict__ W0,
                                            const float* __restrict__ W1,
                                            const float* __restrict__ W2,
                                            const float* __restrict__ W3,
                                            u16* __restrict__ o0,
                                            u16* __restrict__ o1,
                                            u16* __restrict__ o2,
                                            u16* __restrict__ o3) {
    __shared__ float tS[32][33];
    const int bid = blockIdx.x;
    if (bid < 4096) {                  // convert x: 1M float4s
        int i = bid * 256 + threadIdx.x;
        float4 f = ((const float4*)x)[i];
        ushort4 u;
        u.x = f2bf(f.x); u.y = f2bf(f.y); u.z = f2bf(f.z); u.w = f2bf(f.w);
        ((ushort4*)xb)[i] = u;
    } else {                           // transpose W: 4 x (32x32 grid of 32x32 tiles)
        const int id  = bid - 4096;
        const int z   = id >> 10;
        const int rem = id & 1023;
        const float* in = z == 0 ? W0 : z == 1 ? W1 : z == 2 ? W2 : W3;
        u16* out       = z == 0 ? o0 : z == 1 ? o1 : z == 2 ? o2 : o3;
        const int bx = (rem & 31) * 32, by = (rem >> 5) * 32;
        const int xx = threadIdx.x & 31, yy = threadIdx.x >> 5;
        #pragma unroll
        for (int j = 0; j < 4; j++)
            tS[yy + j * 8][xx] = in[(long)(by + yy + j * 8) * HID_ + bx + xx];
        __syncthreads();
        #pragma unroll
        for (int j = 0; j < 4; j++)
            out[(long)(bx + yy + j * 8) * HID_ + by + xx] = f2bf(tS[xx][yy + j * 8]);
    }
}

// ---------------- bf16 MFMA GEMM 128x128, BK=64, swizzled LDS (m173 pattern) ----------------
__global__ __launch_bounds__(256, 3) void gemm_qkv(const u16* __restrict__ A,
                                                   const u16* __restrict__ Bt,
                                                   u16* __restrict__ outb,
                                                   const float* __restrict__ cosb,
                                                   const float* __restrict__ sinb,
                                                   int K) {
    __shared__ u16 As[128 * 64];
    __shared__ u16 Bs[128 * 64];
    const int t = threadIdx.x;
    const int lane = t & 63;
    const int w = t >> 6;
    const int qlane = lane & 15, grp = lane >> 4;
    const int m0 = blockIdx.y * 128, n0 = blockIdx.x * 128;
    const int wr = w >> 1, wc = w & 1;

    f32x4 acc[4][4];
    #pragma unroll
    for (int i = 0; i < 4; i++)
        #pragma unroll
        for (int j = 0; j < 4; j++) acc[i][j] = (f32x4){0.f, 0.f, 0.f, 0.f};

    const int srow = lane >> 3;                  // 0..7 (row within 8-row chunk)
    const int scol = ((lane & 7) ^ srow) * 8;    // pre-swizzled source col (bf16)
    const int swa  = (qlane & 7) << 4;           // read-side XOR (bytes)
    const int nkt = K >> 6;
    for (int kt = 0; kt < nkt; kt++) {
        const int k0 = kt << 6;
        #pragma unroll
        for (int c = 0; c < 4; c++) {
            const int chunk = w * 4 + c;         // 16 chunks x 8 rows = 128 rows
            const int row = chunk * 8 + srow;
            gll16(A  + (long)(m0 + row) * K + k0 + scol, As + chunk * 512);
            gll16(Bt + (long)(n0 + row) * K + k0 + scol, Bs + chunk * 512);
        }
        __syncthreads();
        #pragma unroll
        for (int ks = 0; ks < 2; ks++) {
            bf16x8 af[4], bfr[4];
            #pragma unroll
            for (int i = 0; i < 4; i++) {
                af[i]  = *(const bf16x8*)((const unsigned char*)As
                         + (wr * 64 + i * 16 + qlane) * 128 + ((ks * 64 + grp * 16) ^ swa));
                bfr[i] = *(const bf16x8*)((const unsigned char*)Bs
                         + (wc * 64 + i * 16 + qlane) * 128 + ((ks * 64 + grp * 16) ^ swa));
            }
            #pragma unroll
            for (int mf = 0; mf < 4; mf++)
                #pragma unroll
                for (int nf = 0; nf < 4; nf++)
                    acc[mf][nf] = __builtin_amdgcn_mfma_f32_16x16x32_bf16(bfr[nf], af[mf], acc[mf][nf], 0, 0, 0);
        }
        __syncthreads();
    }

    const int gnb = n0 + wc * 64;
    const bool isqk = gnb < 2048;
    const bool isq  = gnb < 1024;
    const float QS = 0.125f * LOG2E;
    #pragma unroll
    for (int mf = 0; mf < 4; mf++) {
        const int m = m0 + wr * 64 + mf * 16 + qlane;
        if (isqk) {
            const int s = m & (S_ - 1);
            const float* cr = cosb + s * 64;
            const float* sr = sinb + s * 64;
            #pragma unroll
            for (int nf2 = 0; nf2 < 2; nf2++) {
                #pragma unroll
                for (int r = 0; r < 4; r++) {
                    const int d = nf2 * 16 + grp * 4 + r;
                    float lo = acc[mf][nf2][r], hi = acc[mf][nf2 + 2][r];
                    float nlo = lo * cr[d]      - hi * sr[d];
                    float nhi = hi * cr[d + 32] + lo * sr[d + 32];
                    if (isq) { nlo *= QS; nhi *= QS; }
                    acc[mf][nf2][r]     = nlo;
                    acc[mf][nf2 + 2][r] = nhi;
                }
            }
        }
        #pragma unroll
        for (int nf = 0; nf < 4; nf++) {
            const int gn = gnb + nf * 16 + grp * 4;
            ushort4 o4;
            o4.x = f2bf(acc[mf][nf][0]); o4.y = f2bf(acc[mf][nf][1]);
            o4.z = f2bf(acc[mf][nf][2]); o4.w = f2bf(acc[mf][nf][3]);
            *(ushort4*)&outb[((long)(gn >> 10)) * ((long)4096 * 1024) + (long)m * 1024 + (gn & 1023)] = o4;
        }
    }
}

// ---------------- bf16 MFMA GEMM 128x64, BK=64 swizzled (f32 out) for ctx @ Wo ----------------
__global__ __launch_bounds__(256, 3) void gemm_n64(const u16* __restrict__ A,
                                                   const u16* __restrict__ Bt,
                                                   float* __restrict__ outf,
                                                   int K) {
    __shared__ u16 As[128 * 64];
    __shared__ u16 Bs[64 * 64];
    const int t = threadIdx.x;
    const int lane = t & 63;
    const int w = t >> 6;
    const int qlane = lane & 15, grp = lane >> 4;
    const int m0 = blockIdx.y * 128, n0 = blockIdx.x * 64;

    f32x4 acc[2][4];
    #pragma unroll
    for (int i = 0; i < 2; i++)
        #pragma unroll
        for (int j = 0; j < 4; j++) acc[i][j] = (f32x4){0.f, 0.f, 0.f, 0.f};

    const int srow = lane >> 3;                  // 0..7
    const int scol = ((lane & 7) ^ srow) * 8;    // pre-swizzled source col
    const int swa  = (qlane & 7) << 4;
    const int nkt = K >> 6;
    for (int kt = 0; kt < nkt; kt++) {
        const int k0 = kt << 6;
        #pragma unroll
        for (int c = 0; c < 4; c++) {
            const int chunk = w * 4 + c;         // 16 chunks x 8 rows = 128 rows
            gll16(A + (long)(m0 + chunk * 8 + srow) * K + k0 + scol, As + chunk * 512);
        }
        #pragma unroll
        for (int c = 0; c < 2; c++) {
            const int chunk = w * 2 + c;         // 8 chunks x 8 rows = 64 rows
            gll16(Bt + (long)(n0 + chunk * 8 + srow) * K + k0 + scol, Bs + chunk * 512);
        }
        __syncthreads();
        #pragma unroll
        for (int ks = 0; ks < 2; ks++) {
            bf16x8 af[2], bfr[4];
            #pragma unroll
            for (int i = 0; i < 2; i++)
                af[i] = *(const bf16x8*)((const unsigned char*)As
                        + (w * 32 + i * 16 + qlane) * 128 + ((ks * 64 + grp * 16) ^ swa));
            #pragma unroll
            for (int i = 0; i < 4; i++)
                bfr[i] = *(const bf16x8*)((const unsigned char*)Bs
                         + (i * 16 + qlane) * 128 + ((ks * 64 + grp * 16) ^ swa));
            #pragma unroll
            for (int mf = 0; mf < 2; mf++)
                #pragma unroll
                for (int nf = 0; nf < 4; nf++)
                    acc[mf][nf] = __builtin_amdgcn_mfma_f32_16x16x32_bf16(bfr[nf], af[mf], acc[mf][nf], 0, 0, 0);
        }
        __syncthreads();
    }

    #pragma unroll
    for (int mf = 0; mf < 2; mf++) {
        const int m = m0 + w * 32 + mf * 16 + qlane;
        #pragma unroll
        for (int nf = 0; nf < 4; nf++) {
            float4 o4;
            o4.x = acc[mf][nf][0]; o4.y = acc[mf][nf][1];
            o4.z = acc[mf][nf][2]; o4.w = acc[mf][nf][3];
            *(float4*)&outf[(long)m * 1024 + n0 + nf * 16 + grp * 4] = o4;
        }
    }
}

// ---------------- MFMA flash attention: R14 body + 4-deep buffers, barrier/2-iters ----------------
// Iter kt reads buf[kt&3], writes buf[(kt+2)&3]; __syncthreads only on odd kt.
// Between barriers waves span iters {i,i+1}: reads {i,i+1}%4, writes {i+2,i+3}%4
// -> disjoint; overwritten buffer last read 2 iters before preceding barrier.
// Staging granularity per iter unchanged vs R14 (avoids R16's fetch-waste and
// serial-stretch); NT = 2qtb+2 always even -> clean pairs.
__global__ __launch_bounds__(512, 4) void attn_mfma(const u16* __restrict__ q,
                                                    const u16* __restrict__ k,
                                                    const u16* __restrict__ v,
                                                    const float* __restrict__ rel_bias,
                                                    u16* __restrict__ ctx) {
    __shared__ __align__(16) unsigned char kS[4][8192];   // K [k][d] bf16, swzK
    __shared__ __align__(16) unsigned char vS[4][8192];   // V^T [d][k] bf16, swzV
    __shared__ float bb[4][192];

    const int t    = threadIdx.x;
    const int lane = t & 63;
    const int w    = t >> 6;                     // 0..7
    const int n    = blockIdx.x;                 // 512 blocks
    const int xcd  = n & 7;
    const int hbhi = (n >> 7) & 3;
    int qtb        = (n >> 3) & 15;
    if (hbhi & 2) qtb = 15 - qtb;                // zigzag load balance
    const int hb   = xcd + (hbhi << 3);          // 4 heads per XCD slot
    const int h    = hb & 15, b = hb >> 4;
    const int q0   = qtb * 128;
    const int wq   = w * 16;
    const int qwq  = q0 + wq;
    const int qlane = lane & 15;
    const int grp   = lane >> 4;

    const long bhbase = ((long)b * S_ * H_ + h) * D_;
    const float bfar  = rel_bias[31 * H_ + h] * LOG2E;

    // staging coords
    const int kr  = t >> 3,        kc  = (t & 7) * 8;    // K: 1 row, 8 cols (b128)
    const int vrb = (t >> 5) * 4,  vcp = (t & 31) * 2;   // V: 4 rows x 2 cols

    bf16x8 qf0, qf1;
    {
        const u16* qrow = q + bhbase + (long)(qwq + qlane) * HD_;
        qf0 = *(const bf16x8*)(qrow + grp * 8);
        qf1 = *(const bf16x8*)(qrow + 32 + grp * 8);
    }

    f32x4 oacc[4];                                // O^T: row d, col q=qlane
    #pragma unroll
    for (int db = 0; db < 4; db++) oacc[db] = (f32x4){0.f, 0.f, 0.f, 0.f};
    float m_run = -1.0e30f, l_run = 0.f;

    bf16x8 kreg;
    unsigned vreg[4];
    float breg = 0.f;

    auto prefetch = [&](int k0, bool needb) {
        kreg = *(const bf16x8*)(k + bhbase + (long)(k0 + kr) * HD_ + kc);
        const u16* vp = v + bhbase + (long)(k0 + vrb) * HD_ + vcp;
        #pragma unroll
        for (int i = 0; i < 4; i++)
            vreg[i] = *(const unsigned*)(vp + (long)i * HD_);
        if (needb && t < 192) {
            int rp = (q0 - 63) + t - k0;
            float bv = 0.f;
            if (rp >= 0) {
                int bucket;
                if (rp < 16) bucket = rp;
                else {
                    int lg = (int)(logf((float)rp * 0.0625f) * 7.69437361f);
                    bucket = 16 + lg;
                    if (bucket > 31) bucket = 31;
                }
                bv = rel_bias[bucket * H_ + h] * LOG2E;
            }
            breg = bv;
        }
    };
    auto writetile = [&](int buf, bool needb) {
        *(bf16x8*)(kS[buf] + swzK(kr, kc * 2)) = kreg;
        ushort2 a0 = __builtin_bit_cast(ushort2, vreg[0]);
        ushort2 a1 = __builtin_bit_cast(ushort2, vreg[1]);
        ushort2 a2 = __builtin_bit_cast(ushort2, vreg[2]);
        ushort2 a3 = __builtin_bit_cast(ushort2, vreg[3]);
        ushort4 d0; d0.x = a0.x; d0.y = a1.x; d0.z = a2.x; d0.w = a3.x;
        ushort4 d1; d1.x = a0.y; d1.y = a1.y; d1.z = a2.y; d1.w = a3.y;
        *(ushort4*)(vS[buf] + swzV(vcp,     vrb * 2)) = d0;
        *(ushort4*)(vS[buf] + swzV(vcp + 1, vrb * 2)) = d1;
        if (needb && t < 192) bb[buf][t] = breg;
    };

    const int NT = 2 * qtb + 2;
    // prologue: stage tiles 0 and 1 (NT >= 2 always)
    prefetch(0, q0 < 176);
    writetile(0, q0 < 176);
    prefetch(64, (q0 - 64) < 176);
    writetile(1, (q0 - 64) < 176);
    __syncthreads();

    for (int kt = 0; kt < NT; kt++) {
        const int k0 = kt * 64;
        const int cur = kt & 3;
        const bool has_next = (kt + 2) < NT;
        const bool needb_n  = (q0 - (k0 + 128)) < 176;
        if (has_next) prefetch(k0 + 128, needb_n);

        const bool skip = k0 > qwq + 15;
        if (!skip) {
            const bool use_bias = (qwq - k0) < 176;
            const bool is_diag  = (k0 + 63) > qwq;

            __builtin_amdgcn_s_setprio(1);
            f32x4 sacc[4];
            #pragma unroll
            for (int kb = 0; kb < 4; kb++) {
                sacc[kb] = (f32x4){0.f, 0.f, 0.f, 0.f};
                bf16x8 kf0 = *(const bf16x8*)(kS[cur] + swzK(kb * 16 + qlane, grp * 16));
                bf16x8 kf1 = *(const bf16x8*)(kS[cur] + swzK(kb * 16 + qlane, 64 + grp * 16));
                sacc[kb] = __builtin_amdgcn_mfma_f32_16x16x32_bf16(kf0, qf0, sacc[kb], 0, 0, 0);
                sacc[kb] = __builtin_amdgcn_mfma_f32_16x16x32_bf16(kf1, qf1, sacc[kb], 0, 0, 0);
            }
            __builtin_amdgcn_s_setprio(0);

            float pv_[4][4];
            float tmax = -1.0e30f;
            #pragma unroll
            for (int kb = 0; kb < 4; kb++) {
                #pragma unroll
                for (int r = 0; r < 4; r++) {
                    float s = sacc[kb][r];               // log2 domain
                    if (use_bias) {
                        const int k_l = kb * 16 + grp * 4 + r;
                        s += bb[cur][wq + qlane - k_l + 63];
                        if (is_diag)
                            s = ((k0 + k_l) <= (qwq + qlane)) ? s : -1.0e9f;
                    }
                    pv_[kb][r] = s;
                }
                tmax = fmaxf(tmax,
                       fmaxf(fmaxf(pv_[kb][0], pv_[kb][1]), fmaxf(pv_[kb][2], pv_[kb][3])));
            }
            tmax = fmaxf(tmax, __shfl_xor(tmax, 16));
            tmax = fmaxf(tmax, __shfl_xor(tmax, 32));

            const float bofs = use_bias ? 0.f : bfar;
            const float teff = tmax + bofs;
            float msub;
            if (__all(teff <= m_run + 11.5f)) {          // defer (2^11.5 ~ e^8)
                msub = m_run - bofs;
            } else {
                float mnew  = fmaxf(m_run, teff);
                float scale = __builtin_amdgcn_exp2f(m_run - mnew);
                l_run *= scale;
                #pragma unroll
                for (int db = 0; db < 4; db++)
                    #pragma unroll
                    for (int r = 0; r < 4; r++) oacc[db][r] *= scale;   // per-lane q
                m_run = mnew;
                msub = mnew - bofs;
            }

            float tsum = 0.f;
            #pragma unroll
            for (int kb = 0; kb < 4; kb++)
                #pragma unroll
                for (int r = 0; r < 4; r++) {
                    float p = __builtin_amdgcn_exp2f(pv_[kb][r] - msub);
                    pv_[kb][r] = p;
                    tsum += p;
                }
            tsum += __shfl_xor(tsum, 16);
            tsum += __shfl_xor(tsum, 32);
            l_run += tsum;

            bf16x8 pf[2];
            #pragma unroll
            for (int ks = 0; ks < 2; ks++) {
                unsigned u0 = cvtpk(pv_[2 * ks][0], pv_[2 * ks][1]);
                unsigned u1 = cvtpk(pv_[2 * ks][2], pv_[2 * ks][3]);
                unsigned u2 = cvtpk(pv_[2 * ks + 1][0], pv_[2 * ks + 1][1]);
                unsigned u3 = cvtpk(pv_[2 * ks + 1][2], pv_[2 * ks + 1][3]);
                pf[ks] = __builtin_bit_cast(bf16x8, (uint4v){u0, u1, u2, u3});
            }

            __builtin_amdgcn_s_setprio(1);
            #pragma unroll
            for (int db = 0; db < 4; db++) {
                #pragma unroll
                for (int ks = 0; ks < 2; ks++) {
                    bf16x4 lo = *(const bf16x4*)(vS[cur] + swzV(db * 16 + qlane, ks * 64 + grp * 8));
                    bf16x4 hi = *(const bf16x4*)(vS[cur] + swzV(db * 16 + qlane, ks * 64 + 32 + grp * 8));
                    bf16x8 vf = __builtin_shufflevector(lo, hi, 0, 1, 2, 3, 4, 5, 6, 7);
                    oacc[db] = __builtin_amdgcn_mfma_f32_16x16x32_bf16(vf, pf[ks], oacc[db], 0, 0, 0);
                }
            }
            __builtin_amdgcn_s_setprio(0);
        }

        if (has_next) writetile((kt + 2) & 3, needb_n);
        if (kt & 1) __syncthreads();             // barrier every 2nd iteration
    }

    // ---- epilogue: per-lane 1/l; O^T row d = db*16+grp*4+r, col q = qlane ----
    const float inv = 1.0f / l_run;
    u16* dst = ctx + (long)(b * S_ + qwq + qlane) * HID_ + h * D_;
    #pragma unroll
    for (int db = 0; db < 4; db++) {
        ushort4 o4;
        o4.x = f2bf(oacc[db][0] * inv);
        o4.y = f2bf(oacc[db][1] * inv);
        o4.z = f2bf(oacc[db][2] * inv);
        o4.w = f2bf(oacc[db][3] * inv);
        *(ushort4*)(dst + db * 16 + grp * 4) = o4;
    }
}

extern "C" void kernel_launch(void* const* d_in, const int* in_sizes, int n_in,
                              void* d_out, int out_size, void* d_ws, size_t ws_size,
                              hipStream_t stream) {
    const float* x    = (const float*)d_in[0];
    const float* Wq   = (const float*)d_in[1];
    const float* Wk   = (const float*)d_in[2];
    const float* Wv   = (const float*)d_in[3];
    const float* Wo   = (const float*)d_in[4];
    const float* rb   = (const float*)d_in[5];
    const float* cosb = (const float*)d_in[6];
    const float* sinb = (const float*)d_in[7];
    float* out = (float*)d_out;

    char* wsb = (char*)d_ws;
    u16* xb    = (u16*)(wsb);
    u16* wqkvT = (u16*)(wsb + (8L  << 20));
    u16* woT   = (u16*)(wsb + (14L << 20));
    u16* qb    = (u16*)(wsb + (16L << 20));
    u16* kb    = (u16*)(wsb + (24L << 20));
    u16* vb    = (u16*)(wsb + (32L << 20));
    u16* ctxb  = (u16*)(wsb + (40L << 20));

    hipLaunchKernelGGL(prep, dim3(4096 + 4096), dim3(256), 0, stream,
                       x, xb, Wq, Wk, Wv, Wo,
                       wqkvT, wqkvT + (1L << 20), wqkvT + (2L << 20), woT);
    hipLaunchKernelGGL(gemm_qkv, dim3(24, 32), dim3(256), 0, stream,
                       xb, wqkvT, qb, cosb, sinb, HID_);
    hipLaunchKernelGGL(attn_mfma, dim3(512), dim3(512), 0, stream,
                       qb, kb, vb, rb, ctxb);
    hipLaunchKernelGGL(gemm_n64, dim3(16, 32), dim3(256), 0, stream,
                       ctxb, woT, out, HID_);
}

// Round 21
// 116.632 us; speedup vs baseline: 1.4573x; 1.0004x over previous
//
#include <hip/hip_runtime.h>
#include <hip/hip_bf16.h>
#include <math.h>

#define B_   2
#define S_   2048
#define HID_ 1024
#define H_   16
#define D_   64
#define HD_  (H_ * D_)

typedef __attribute__((ext_vector_type(8))) short bf16x8;
typedef __attribute__((ext_vector_type(4))) short bf16x4;
typedef __attribute__((ext_vector_type(4))) float f32x4;
typedef __attribute__((ext_vector_type(4))) unsigned uint4v;
typedef unsigned short u16;

#define LOG2E 1.44269504088896f

static __device__ __forceinline__ u16 f2bf(float f) {
    unsigned u = __builtin_bit_cast(unsigned, f);
    u += 0x7fffu + ((u >> 16) & 1u);          // RNE
    return (u16)(u >> 16);
}
static __device__ __forceinline__ unsigned cvtpk(float lo, float hi) {
    unsigned r;
    asm("v_cvt_pk_bf16_f32 %0, %1, %2" : "=v"(r) : "v"(lo), "v"(hi));
    return r;
}
static __device__ __forceinline__ int swzK(int row, int colbytes) {
    return row * 128 + (colbytes ^ ((row & 7) << 4));
}
static __device__ __forceinline__ int swzV(int row, int colbytes) {
    return row * 128 + (colbytes ^ ((row & 7) << 4) ^ (((row >> 3) & 1) << 3));
}
static __device__ __forceinline__ void gll16(const void* g, void* l) {
    __builtin_amdgcn_global_load_lds(
        (const __attribute__((address_space(1))) unsigned int*)g,
        (__attribute__((address_space(3))) unsigned int*)l, 16, 0, 0);
}

// ---------------- fused preprocessing: x->bf16 AND 4x W transpose->bf16 ----------------
__global__ __launch_bounds__(256) void prep(const float* __restrict__ x,
                                            u16* __restrict__ xb,
                                            const float* __restrict__ W0,
                                            const float* __restrict__ W1,
                                            const float* __restrict__ W2,
                                            const float* __restrict__ W3,
                                            u16* __restrict__ o0,
                                            u16* __restrict__ o1,
                                            u16* __restrict__ o2,
                                            u16* __restrict__ o3) {
    __shared__ float tS[32][33];
    const int bid = blockIdx.x;
    if (bid < 4096) {                  // convert x: 1M float4s
        int i = bid * 256 + threadIdx.x;
        float4 f = ((const float4*)x)[i];
        ushort4 u;
        u.x = f2bf(f.x); u.y = f2bf(f.y); u.z = f2bf(f.z); u.w = f2bf(f.w);
        ((ushort4*)xb)[i] = u;
    } else {                           // transpose W: 4 x (32x32 grid of 32x32 tiles)
        const int id  = bid - 4096;
        const int z   = id >> 10;
        const int rem = id & 1023;
        const float* in = z == 0 ? W0 : z == 1 ? W1 : z == 2 ? W2 : W3;
        u16* out       = z == 0 ? o0 : z == 1 ? o1 : z == 2 ? o2 : o3;
        const int bx = (rem & 31) * 32, by = (rem >> 5) * 32;
        const int xx = threadIdx.x & 31, yy = threadIdx.x >> 5;
        #pragma unroll
        for (int j = 0; j < 4; j++)
            tS[yy + j * 8][xx] = in[(long)(by + yy + j * 8) * HID_ + bx + xx];
        __syncthreads();
        #pragma unroll
        for (int j = 0; j < 4; j++)
            out[(long)(bx + yy + j * 8) * HID_ + by + xx] = f2bf(tS[xx][yy + j * 8]);
    }
}

// ---------------- bf16 MFMA GEMM 128x128, BK=64, swizzled LDS (m173 pattern) ----------------
__global__ __launch_bounds__(256, 3) void gemm_qkv(const u16* __restrict__ A,
                                                   const u16* __restrict__ Bt,
                                                   u16* __restrict__ outb,
                                                   const float* __restrict__ cosb,
                                                   const float* __restrict__ sinb,
                                                   int K) {
    __shared__ u16 As[128 * 64];
    __shared__ u16 Bs[128 * 64];
    const int t = threadIdx.x;
    const int lane = t & 63;
    const int w = t >> 6;
    const int qlane = lane & 15, grp = lane >> 4;
    const int m0 = blockIdx.y * 128, n0 = blockIdx.x * 128;
    const int wr = w >> 1, wc = w & 1;

    f32x4 acc[4][4];
    #pragma unroll
    for (int i = 0; i < 4; i++)
        #pragma unroll
        for (int j = 0; j < 4; j++) acc[i][j] = (f32x4){0.f, 0.f, 0.f, 0.f};

    const int srow = lane >> 3;                  // 0..7 (row within 8-row chunk)
    const int scol = ((lane & 7) ^ srow) * 8;    // pre-swizzled source col (bf16)
    const int swa  = (qlane & 7) << 4;           // read-side XOR (bytes)
    const int nkt = K >> 6;
    for (int kt = 0; kt < nkt; kt++) {
        const int k0 = kt << 6;
        #pragma unroll
        for (int c = 0; c < 4; c++) {
            const int chunk = w * 4 + c;         // 16 chunks x 8 rows = 128 rows
            const int row = chunk * 8 + srow;
            gll16(A  + (long)(m0 + row) * K + k0 + scol, As + chunk * 512);
            gll16(Bt + (long)(n0 + row) * K + k0 + scol, Bs + chunk * 512);
        }
        __syncthreads();
        #pragma unroll
        for (int ks = 0; ks < 2; ks++) {
            bf16x8 af[4], bfr[4];
            #pragma unroll
            for (int i = 0; i < 4; i++) {
                af[i]  = *(const bf16x8*)((const unsigned char*)As
                         + (wr * 64 + i * 16 + qlane) * 128 + ((ks * 64 + grp * 16) ^ swa));
                bfr[i] = *(const bf16x8*)((const unsigned char*)Bs
                         + (wc * 64 + i * 16 + qlane) * 128 + ((ks * 64 + grp * 16) ^ swa));
            }
            #pragma unroll
            for (int mf = 0; mf < 4; mf++)
                #pragma unroll
                for (int nf = 0; nf < 4; nf++)
                    acc[mf][nf] = __builtin_amdgcn_mfma_f32_16x16x32_bf16(bfr[nf], af[mf], acc[mf][nf], 0, 0, 0);
        }
        __syncthreads();
    }

    const int gnb = n0 + wc * 64;
    const bool isqk = gnb < 2048;
    const bool isq  = gnb < 1024;
    const float QS = 0.125f * LOG2E;
    #pragma unroll
    for (int mf = 0; mf < 4; mf++) {
        const int m = m0 + wr * 64 + mf * 16 + qlane;
        if (isqk) {
            const int s = m & (S_ - 1);
            const float* cr = cosb + s * 64;
            const float* sr = sinb + s * 64;
            #pragma unroll
            for (int nf2 = 0; nf2 < 2; nf2++) {
                #pragma unroll
                for (int r = 0; r < 4; r++) {
                    const int d = nf2 * 16 + grp * 4 + r;
                    float lo = acc[mf][nf2][r], hi = acc[mf][nf2 + 2][r];
                    float nlo = lo * cr[d]      - hi * sr[d];
                    float nhi = hi * cr[d + 32] + lo * sr[d + 32];
                    if (isq) { nlo *= QS; nhi *= QS; }
                    acc[mf][nf2][r]     = nlo;
                    acc[mf][nf2 + 2][r] = nhi;
                }
            }
        }
        #pragma unroll
        for (int nf = 0; nf < 4; nf++) {
            const int gn = gnb + nf * 16 + grp * 4;
            ushort4 o4;
            o4.x = f2bf(acc[mf][nf][0]); o4.y = f2bf(acc[mf][nf][1]);
            o4.z = f2bf(acc[mf][nf][2]); o4.w = f2bf(acc[mf][nf][3]);
            *(ushort4*)&outb[((long)(gn >> 10)) * ((long)4096 * 1024) + (long)m * 1024 + (gn & 1023)] = o4;
        }
    }
}

// ---------------- bf16 MFMA GEMM 128x64, BK=64 swizzled (f32 out) for ctx @ Wo ----------------
__global__ __launch_bounds__(256, 3) void gemm_n64(const u16* __restrict__ A,
                                                   const u16* __restrict__ Bt,
                                                   float* __restrict__ outf,
                                                   int K) {
    __shared__ u16 As[128 * 64];
    __shared__ u16 Bs[64 * 64];
    const int t = threadIdx.x;
    const int lane = t & 63;
    const int w = t >> 6;
    const int qlane = lane & 15, grp = lane >> 4;
    const int m0 = blockIdx.y * 128, n0 = blockIdx.x * 64;

    f32x4 acc[2][4];
    #pragma unroll
    for (int i = 0; i < 2; i++)
        #pragma unroll
        for (int j = 0; j < 4; j++) acc[i][j] = (f32x4){0.f, 0.f, 0.f, 0.f};

    const int srow = lane >> 3;                  // 0..7
    const int scol = ((lane & 7) ^ srow) * 8;    // pre-swizzled source col
    const int swa  = (qlane & 7) << 4;
    const int nkt = K >> 6;
    for (int kt = 0; kt < nkt; kt++) {
        const int k0 = kt << 6;
        #pragma unroll
        for (int c = 0; c < 4; c++) {
            const int chunk = w * 4 + c;         // 16 chunks x 8 rows = 128 rows
            gll16(A + (long)(m0 + chunk * 8 + srow) * K + k0 + scol, As + chunk * 512);
        }
        #pragma unroll
        for (int c = 0; c < 2; c++) {
            const int chunk = w * 2 + c;         // 8 chunks x 8 rows = 64 rows
            gll16(Bt + (long)(n0 + chunk * 8 + srow) * K + k0 + scol, Bs + chunk * 512);
        }
        __syncthreads();
        #pragma unroll
        for (int ks = 0; ks < 2; ks++) {
            bf16x8 af[2], bfr[4];
            #pragma unroll
            for (int i = 0; i < 2; i++)
                af[i] = *(const bf16x8*)((const unsigned char*)As
                        + (w * 32 + i * 16 + qlane) * 128 + ((ks * 64 + grp * 16) ^ swa));
            #pragma unroll
            for (int i = 0; i < 4; i++)
                bfr[i] = *(const bf16x8*)((const unsigned char*)Bs
                         + (i * 16 + qlane) * 128 + ((ks * 64 + grp * 16) ^ swa));
            #pragma unroll
            for (int mf = 0; mf < 2; mf++)
                #pragma unroll
                for (int nf = 0; nf < 4; nf++)
                    acc[mf][nf] = __builtin_amdgcn_mfma_f32_16x16x32_bf16(bfr[nf], af[mf], acc[mf][nf], 0, 0, 0);
        }
        __syncthreads();
    }

    #pragma unroll
    for (int mf = 0; mf < 2; mf++) {
        const int m = m0 + w * 32 + mf * 16 + qlane;
        #pragma unroll
        for (int nf = 0; nf < 4; nf++) {
            float4 o4;
            o4.x = acc[mf][nf][0]; o4.y = acc[mf][nf][1];
            o4.z = acc[mf][nf][2]; o4.w = acc[mf][nf][3];
            *(float4*)&outf[(long)m * 1024 + n0 + nf * 16 + grp * 4] = o4;
        }
    }
}

// ---------------- MFMA flash attention: R14 body + 4-deep buffers, barrier/2-iters ----------------
// Iter kt reads buf[kt&3], writes buf[(kt+2)&3]; __syncthreads only on odd kt.
// Between barriers waves span iters {i,i+1}: reads {i,i+1}%4, writes {i+2,i+3}%4
// -> disjoint; overwritten buffer last read 2 iters before preceding barrier.
__global__ __launch_bounds__(512, 4) void attn_mfma(const u16* __restrict__ q,
                                                    const u16* __restrict__ k,
                                                    const u16* __restrict__ v,
                                                    const float* __restrict__ rel_bias,
                                                    u16* __restrict__ ctx) {
    __shared__ __align__(16) unsigned char kS[4][8192];   // K [k][d] bf16, swzK
    __shared__ __align__(16) unsigned char vS[4][8192];   // V^T [d][k] bf16, swzV
    __shared__ float bb[4][192];

    const int t    = threadIdx.x;
    const int lane = t & 63;
    const int w    = t >> 6;                     // 0..7
    const int n    = blockIdx.x;                 // 512 blocks
    const int xcd  = n & 7;
    const int hbhi = (n >> 7) & 3;
    int qtb        = (n >> 3) & 15;
    if (hbhi & 2) qtb = 15 - qtb;                // zigzag load balance
    const int hb   = xcd + (hbhi << 3);          // 4 heads per XCD slot
    const int h    = hb & 15, b = hb >> 4;
    const int q0   = qtb * 128;
    const int wq   = w * 16;
    const int qwq  = q0 + wq;
    const int qlane = lane & 15;
    const int grp   = lane >> 4;

    const long bhbase = ((long)b * S_ * H_ + h) * D_;
    const float bfar  = rel_bias[31 * H_ + h] * LOG2E;

    // staging coords
    const int kr  = t >> 3,        kc  = (t & 7) * 8;    // K: 1 row, 8 cols (b128)
    const int vrb = (t >> 5) * 4,  vcp = (t & 31) * 2;   // V: 4 rows x 2 cols

    bf16x8 qf0, qf1;
    {
        const u16* qrow = q + bhbase + (long)(qwq + qlane) * HD_;
        qf0 = *(const bf16x8*)(qrow + grp * 8);
        qf1 = *(const bf16x8*)(qrow + 32 + grp * 8);
    }

    f32x4 oacc[4];                                // O^T: row d, col q=qlane
    #pragma unroll
    for (int db = 0; db < 4; db++) oacc[db] = (f32x4){0.f, 0.f, 0.f, 0.f};
    float m_run = -1.0e30f, l_run = 0.f;

    bf16x8 kreg;
    unsigned vreg[4];
    float breg = 0.f;

    auto prefetch = [&](int k0, bool needb) {
        kreg = *(const bf16x8*)(k + bhbase + (long)(k0 + kr) * HD_ + kc);
        const u16* vp = v + bhbase + (long)(k0 + vrb) * HD_ + vcp;
        #pragma unroll
        for (int i = 0; i < 4; i++)
            vreg[i] = *(const unsigned*)(vp + (long)i * HD_);
        if (needb && t < 192) {
            int rp = (q0 - 63) + t - k0;
            float bv = 0.f;
            if (rp >= 0) {
                int bucket;
                if (rp < 16) bucket = rp;
                else {
                    int lg = (int)(logf((float)rp * 0.0625f) * 7.69437361f);
                    bucket = 16 + lg;
                    if (bucket > 31) bucket = 31;
                }
                bv = rel_bias[bucket * H_ + h] * LOG2E;
            }
            breg = bv;
        }
    };
    auto writetile = [&](int buf, bool needb) {
        *(bf16x8*)(kS[buf] + swzK(kr, kc * 2)) = kreg;
        ushort2 a0 = __builtin_bit_cast(ushort2, vreg[0]);
        ushort2 a1 = __builtin_bit_cast(ushort2, vreg[1]);
        ushort2 a2 = __builtin_bit_cast(ushort2, vreg[2]);
        ushort2 a3 = __builtin_bit_cast(ushort2, vreg[3]);
        ushort4 d0; d0.x = a0.x; d0.y = a1.x; d0.z = a2.x; d0.w = a3.x;
        ushort4 d1; d1.x = a0.y; d1.y = a1.y; d1.z = a2.y; d1.w = a3.y;
        *(ushort4*)(vS[buf] + swzV(vcp,     vrb * 2)) = d0;
        *(ushort4*)(vS[buf] + swzV(vcp + 1, vrb * 2)) = d1;
        if (needb && t < 192) bb[buf][t] = breg;
    };

    const int NT = 2 * qtb + 2;
    // prologue: stage tiles 0 and 1 (NT >= 2 always)
    prefetch(0, q0 < 176);
    writetile(0, q0 < 176);
    prefetch(64, (q0 - 64) < 176);
    writetile(1, (q0 - 64) < 176);
    __syncthreads();

    for (int kt = 0; kt < NT; kt++) {
        const int k0 = kt * 64;
        const int cur = kt & 3;
        const bool has_next = (kt + 2) < NT;
        const bool needb_n  = (q0 - (k0 + 128)) < 176;
        if (has_next) prefetch(k0 + 128, needb_n);

        const bool skip = k0 > qwq + 15;
        if (!skip) {
            const bool use_bias = (qwq - k0) < 176;
            const bool is_diag  = (k0 + 63) > qwq;

            __builtin_amdgcn_s_setprio(1);
            f32x4 sacc[4];
            #pragma unroll
            for (int kb = 0; kb < 4; kb++) {
                sacc[kb] = (f32x4){0.f, 0.f, 0.f, 0.f};
                bf16x8 kf0 = *(const bf16x8*)(kS[cur] + swzK(kb * 16 + qlane, grp * 16));
                bf16x8 kf1 = *(const bf16x8*)(kS[cur] + swzK(kb * 16 + qlane, 64 + grp * 16));
                sacc[kb] = __builtin_amdgcn_mfma_f32_16x16x32_bf16(kf0, qf0, sacc[kb], 0, 0, 0);
                sacc[kb] = __builtin_amdgcn_mfma_f32_16x16x32_bf16(kf1, qf1, sacc[kb], 0, 0, 0);
            }
            __builtin_amdgcn_s_setprio(0);

            float pv_[4][4];
            float tmax = -1.0e30f;
            #pragma unroll
            for (int kb = 0; kb < 4; kb++) {
                #pragma unroll
                for (int r = 0; r < 4; r++) {
                    float s = sacc[kb][r];               // log2 domain
                    if (use_bias) {
                        const int k_l = kb * 16 + grp * 4 + r;
                        s += bb[cur][wq + qlane - k_l + 63];
                        if (is_diag)
                            s = ((k0 + k_l) <= (qwq + qlane)) ? s : -1.0e9f;
                    }
                    pv_[kb][r] = s;
                }
                tmax = fmaxf(tmax,
                       fmaxf(fmaxf(pv_[kb][0], pv_[kb][1]), fmaxf(pv_[kb][2], pv_[kb][3])));
            }
            tmax = fmaxf(tmax, __shfl_xor(tmax, 16));
            tmax = fmaxf(tmax, __shfl_xor(tmax, 32));

            const float bofs = use_bias ? 0.f : bfar;
            const float teff = tmax + bofs;
            float msub;
            if (__all(teff <= m_run + 11.5f)) {          // defer (2^11.5 ~ e^8)
                msub = m_run - bofs;
            } else {
                float mnew  = fmaxf(m_run, teff);
                float scale = __builtin_amdgcn_exp2f(m_run - mnew);
                l_run *= scale;
                #pragma unroll
                for (int db = 0; db < 4; db++)
                    #pragma unroll
                    for (int r = 0; r < 4; r++) oacc[db][r] *= scale;   // per-lane q
                m_run = mnew;
                msub = mnew - bofs;
            }

            float tsum = 0.f;
            #pragma unroll
            for (int kb = 0; kb < 4; kb++)
                #pragma unroll
                for (int r = 0; r < 4; r++) {
                    float p = __builtin_amdgcn_exp2f(pv_[kb][r] - msub);
                    pv_[kb][r] = p;
                    tsum += p;
                }
            tsum += __shfl_xor(tsum, 16);
            tsum += __shfl_xor(tsum, 32);
            l_run += tsum;

            bf16x8 pf[2];
            #pragma unroll
            for (int ks = 0; ks < 2; ks++) {
                unsigned u0 = cvtpk(pv_[2 * ks][0], pv_[2 * ks][1]);
                unsigned u1 = cvtpk(pv_[2 * ks][2], pv_[2 * ks][3]);
                unsigned u2 = cvtpk(pv_[2 * ks + 1][0], pv_[2 * ks + 1][1]);
                unsigned u3 = cvtpk(pv_[2 * ks + 1][2], pv_[2 * ks + 1][3]);
                pf[ks] = __builtin_bit_cast(bf16x8, (uint4v){u0, u1, u2, u3});
            }

            __builtin_amdgcn_s_setprio(1);
            #pragma unroll
            for (int db = 0; db < 4; db++) {
                #pragma unroll
                for (int ks = 0; ks < 2; ks++) {
                    bf16x4 lo = *(const bf16x4*)(vS[cur] + swzV(db * 16 + qlane, ks * 64 + grp * 8));
                    bf16x4 hi = *(const bf16x4*)(vS[cur] + swzV(db * 16 + qlane, ks * 64 + 32 + grp * 8));
                    bf16x8 vf = __builtin_shufflevector(lo, hi, 0, 1, 2, 3, 4, 5, 6, 7);
                    oacc[db] = __builtin_amdgcn_mfma_f32_16x16x32_bf16(vf, pf[ks], oacc[db], 0, 0, 0);
                }
            }
            __builtin_amdgcn_s_setprio(0);
        }

        if (has_next) writetile((kt + 2) & 3, needb_n);
        if (kt & 1) __syncthreads();             // barrier every 2nd iteration
    }

    // ---- epilogue: per-lane 1/l; O^T row d = db*16+grp*4+r, col q = qlane ----
    const float inv = 1.0f / l_run;
    u16* dst = ctx + (long)(b * S_ + qwq + qlane) * HID_ + h * D_;
    #pragma unroll
    for (int db = 0; db < 4; db++) {
        ushort4 o4;
        o4.x = f2bf(oacc[db][0] * inv);
        o4.y = f2bf(oacc[db][1] * inv);
        o4.z = f2bf(oacc[db][2] * inv);
        o4.w = f2bf(oacc[db][3] * inv);
        *(ushort4*)(dst + db * 16 + grp * 4) = o4;
    }
}

extern "C" void kernel_launch(void* const* d_in, const int* in_sizes, int n_in,
                              void* d_out, int out_size, void* d_ws, size_t ws_size,
                              hipStream_t stream) {
    const float* x    = (const float*)d_in[0];
    const float* Wq   = (const float*)d_in[1];
    const float* Wk   = (const float*)d_in[2];
    const float* Wv   = (const float*)d_in[3];
    const float* Wo   = (const float*)d_in[4];
    const float* rb   = (const float*)d_in[5];
    const float* cosb = (const float*)d_in[6];
    const float* sinb = (const float*)d_in[7];
    float* out = (float*)d_out;

    char* wsb = (char*)d_ws;
    u16* xb    = (u16*)(wsb);
    u16* wqkvT = (u16*)(wsb + (8L  << 20));
    u16* woT   = (u16*)(wsb + (14L << 20));
    u16* qb    = (u16*)(wsb + (16L << 20));
    u16* kb    = (u16*)(wsb + (24L << 20));
    u16* vb    = (u16*)(wsb + (32L << 20));
    u16* ctxb  = (u16*)(wsb + (40L << 20));

    hipLaunchKernelGGL(prep, dim3(4096 + 4096), dim3(256), 0, stream,
                       x, xb, Wq, Wk, Wv, Wo,
                       wqkvT, wqkvT + (1L << 20), wqkvT + (2L << 20), woT);
    hipLaunchKernelGGL(gemm_qkv, dim3(24, 32), dim3(256), 0, stream,
                       xb, wqkvT, qb, cosb, sinb, HID_);
    hipLaunchKernelGGL(attn_mfma, dim3(512), dim3(512), 0, stream,
                       qb, kb, vb, rb, ctxb);
    hipLaunchKernelGGL(gemm_n64, dim3(16, 32), dim3(256), 0, stream,
                       ctxb, woT, out, HID_);
}